// Round 1
// baseline (7741.766 us; speedup 1.0000x reference)
//
#include <hip/hip_runtime.h>
#include <hip/hip_bf16.h>

#define B_  16
#define S_  512
#define V_  512
#define H_  1024
#define NL_ 8
#define NH_ 16
#define DH_ 64
#define F_  4096

typedef __attribute__((ext_vector_type(8))) short bf16x8;
typedef __attribute__((ext_vector_type(4))) float f32x4;

__device__ __forceinline__ float gelu_tanh(float x) {
  float x3 = x * x * x;
  return 0.5f * x * (1.0f + tanhf(0.7978845608028654f * (x + 0.044715f * x3)));
}

// ---------------- weight transpose + fp32->bf16 ----------------
// W: (L, K, N) fp32  ->  WT: (L, N, K) bf16
__global__ __launch_bounds__(256) void transpose_cvt(const float* __restrict__ W,
                                                     __hip_bfloat16* __restrict__ WT,
                                                     int K, int N) {
  __shared__ float tile[32][33];
  int l = blockIdx.z;
  int k0 = blockIdx.y * 32, n0 = blockIdx.x * 32;
  const float* Wl = W + (size_t)l * K * N;
  __hip_bfloat16* WTl = WT + (size_t)l * N * K;
  int tx = threadIdx.x, ty = threadIdx.y;
  #pragma unroll
  for (int i = 0; i < 32; i += 8)
    tile[ty + i][tx] = Wl[(size_t)(k0 + ty + i) * N + n0 + tx];
  __syncthreads();
  #pragma unroll
  for (int i = 0; i < 32; i += 8)
    WTl[(size_t)(n0 + ty + i) * K + k0 + tx] = __float2bfloat16(tile[tx][ty + i]);
}

__global__ __launch_bounds__(256) void cvt_bf16(const float* __restrict__ in,
                                                __hip_bfloat16* __restrict__ out) {
  int i = (blockIdx.x * 256 + threadIdx.x) * 4;
  float4 v = *(const float4*)(in + i);
  out[i + 0] = __float2bfloat16(v.x);
  out[i + 1] = __float2bfloat16(v.y);
  out[i + 2] = __float2bfloat16(v.z);
  out[i + 3] = __float2bfloat16(v.w);
}

// ---------------- embedding ----------------
__global__ __launch_bounds__(256) void embed_k(const int* __restrict__ ids,
                                               const float* __restrict__ emb,
                                               float* __restrict__ x) {
  int t = blockIdx.x;
  int v = ids[t];
  int d = threadIdx.x * 4;
  float4 val = *(const float4*)(emb + (size_t)v * H_ + d);
  *(float4*)(x + (size_t)t * H_ + d) = val;
}

// ---------------- layernorm (fp32 in, bf16 out) ----------------
__global__ __launch_bounds__(256) void ln_k(const float* __restrict__ x,
                                            const float* __restrict__ g,
                                            const float* __restrict__ b,
                                            __hip_bfloat16* __restrict__ out) {
  int t = blockIdx.x;
  const float* xr = x + (size_t)t * H_;
  float4 v = ((const float4*)xr)[threadIdx.x];
  float s = v.x + v.y + v.z + v.w;
  float q = v.x * v.x + v.y * v.y + v.z * v.z + v.w * v.w;
  #pragma unroll
  for (int off = 32; off; off >>= 1) {
    s += __shfl_down(s, off);
    q += __shfl_down(q, off);
  }
  __shared__ float ps[4], pq[4];
  __shared__ float mu_s, rstd_s;
  int wave = threadIdx.x >> 6, lane = threadIdx.x & 63;
  if (lane == 0) { ps[wave] = s; pq[wave] = q; }
  __syncthreads();
  if (threadIdx.x == 0) {
    float S = ps[0] + ps[1] + ps[2] + ps[3];
    float Q = pq[0] + pq[1] + pq[2] + pq[3];
    float mu = S * (1.0f / H_);
    float var = Q * (1.0f / H_) - mu * mu;
    mu_s = mu;
    rstd_s = rsqrtf(var + 1e-5f);
  }
  __syncthreads();
  float mu = mu_s, rstd = rstd_s;
  int d = threadIdx.x * 4;
  float4 gv = ((const float4*)g)[threadIdx.x];
  float4 bv = ((const float4*)b)[threadIdx.x];
  __hip_bfloat16* op = out + (size_t)t * H_ + d;
  op[0] = __float2bfloat16((v.x - mu) * rstd * gv.x + bv.x);
  op[1] = __float2bfloat16((v.y - mu) * rstd * gv.y + bv.y);
  op[2] = __float2bfloat16((v.z - mu) * rstd * gv.z + bv.z);
  op[3] = __float2bfloat16((v.w - mu) * rstd * gv.w + bv.w);
}

// ---------------- GEMM: C = A(MxK) * BT(NxK)^T  [bf16 MFMA] ----------------
// MODE 0: bf16 out + bias; 1: bf16 out + bias + gelu; 2: fp32 out (+bias if set);
// MODE 3: fp32 residual add (C += A*B + bias)
template <int MODE>
__global__ __launch_bounds__(256) void gemm_bt(const __hip_bfloat16* __restrict__ A,
                                               const __hip_bfloat16* __restrict__ BT,
                                               const float* __restrict__ bias,
                                               void* __restrict__ Cv,
                                               int M, int N, int K) {
  constexpr int BM = 128, BN = 128, BK = 32, LDA = BK + 8;  // +8 bf16 pad (16B)
  __shared__ __hip_bfloat16 As[BM * LDA];
  __shared__ __hip_bfloat16 Bs[BN * LDA];
  const int tid = threadIdx.x;
  const int m0 = blockIdx.y * BM, n0 = blockIdx.x * BN;
  const int wave = tid >> 6, lane = tid & 63;
  const int wr = (wave >> 1) * 64, wc = (wave & 1) * 64;
  const int quad = lane >> 4, l16 = lane & 15;
  const int lrow = tid >> 1, lcol = (tid & 1) * 16;

  f32x4 acc[4][4];
  #pragma unroll
  for (int i = 0; i < 4; i++)
    #pragma unroll
    for (int j = 0; j < 4; j++) acc[i][j] = (f32x4){0.f, 0.f, 0.f, 0.f};

  const uint4* Ag = (const uint4*)(A + (size_t)(m0 + lrow) * K + lcol);
  const uint4* Bg = (const uint4*)(BT + (size_t)(n0 + lrow) * K + lcol);

  for (int k0 = 0; k0 < K; k0 += BK) {
    uint4 a0 = Ag[0], a1 = Ag[1];
    uint4 b0 = Bg[0], b1 = Bg[1];
    __syncthreads();
    *(uint4*)(&As[lrow * LDA + lcol]) = a0;
    *(uint4*)(&As[lrow * LDA + lcol + 8]) = a1;
    *(uint4*)(&Bs[lrow * LDA + lcol]) = b0;
    *(uint4*)(&Bs[lrow * LDA + lcol + 8]) = b1;
    __syncthreads();
    bf16x8 af[4], bfr[4];
    #pragma unroll
    for (int mt = 0; mt < 4; mt++)
      af[mt] = *(const bf16x8*)(&As[(wr + mt * 16 + l16) * LDA + quad * 8]);
    #pragma unroll
    for (int nt = 0; nt < 4; nt++)
      bfr[nt] = *(const bf16x8*)(&Bs[(wc + nt * 16 + l16) * LDA + quad * 8]);
    #pragma unroll
    for (int mt = 0; mt < 4; mt++)
      #pragma unroll
      for (int nt = 0; nt < 4; nt++)
        acc[mt][nt] = __builtin_amdgcn_mfma_f32_16x16x32_bf16(af[mt], bfr[nt], acc[mt][nt], 0, 0, 0);
    Ag += 4;
    Bg += 4;
  }

  #pragma unroll
  for (int mt = 0; mt < 4; mt++) {
    #pragma unroll
    for (int nt = 0; nt < 4; nt++) {
      int col = n0 + wc + nt * 16 + l16;
      float bv = bias ? bias[col] : 0.f;
      #pragma unroll
      for (int rr = 0; rr < 4; rr++) {
        int row = m0 + wr + mt * 16 + quad * 4 + rr;
        float v = acc[mt][nt][rr] + bv;
        if constexpr (MODE == 0) {
          ((__hip_bfloat16*)Cv)[(size_t)row * N + col] = __float2bfloat16(v);
        } else if constexpr (MODE == 1) {
          ((__hip_bfloat16*)Cv)[(size_t)row * N + col] = __float2bfloat16(gelu_tanh(v));
        } else if constexpr (MODE == 2) {
          ((float*)Cv)[(size_t)row * N + col] = v;
        } else {
          ((float*)Cv)[(size_t)row * N + col] += v;
        }
      }
    }
  }
}

// ---------------- fused attention (fp32, flash-style) ----------------
// qkv: (B*S, 3H) bf16; out: (B*S, H) bf16. One block per (b, head, 32-row q tile).
__global__ __launch_bounds__(256) void attn_k(const __hip_bfloat16* __restrict__ qkv,
                                              const int* __restrict__ split_positions,
                                              __hip_bfloat16* __restrict__ out) {
  int bid = blockIdx.x;
  int qt = bid & 15;
  int hh = (bid >> 4) & 15;
  int b = bid >> 8;
  int sp = split_positions[b];
  int i0 = qt * 32;
  int tid = threadIdx.x;
  int r = tid >> 3;  // q row in tile (0..31)
  int c = tid & 7;   // dim chunk (0..7), dims c*8..c*8+7

  __shared__ float Qs[32][68];
  __shared__ float Ks[64][68];
  __shared__ float Vs[64][68];
  __shared__ float Sc[32][65];
  __shared__ float rowm[32], rowl[32], alpha_s[32];
  __shared__ float pmax[32][8], psum[32][8];

  const float slope = exp2f(-0.5f * (float)(hh + 1));
  const size_t base = (size_t)b * S_ * (3 * H_) + (size_t)hh * DH_;
  const int i_row = i0 + r;

  // stage Q (scaled)
  {
    const __hip_bfloat16* qp = qkv + base + (size_t)i_row * (3 * H_) + c * 8;
    uint4 u = *(const uint4*)qp;
    const unsigned* uu = (const unsigned*)&u;
    #pragma unroll
    for (int i = 0; i < 4; i++) {
      float lo = __uint_as_float(uu[i] << 16);
      float hi = __uint_as_float(uu[i] & 0xffff0000u);
      Qs[r][c * 8 + 2 * i + 0] = lo * 0.125f;
      Qs[r][c * 8 + 2 * i + 1] = hi * 0.125f;
    }
  }
  if (tid < 32) { rowm[tid] = -INFINITY; rowl[tid] = 0.f; }

  float o[8] = {0, 0, 0, 0, 0, 0, 0, 0};
  int ktiles = ((i0 + 31) >> 6) + 1;

  for (int kt = 0; kt < ktiles; kt++) {
    int j0 = kt * 64;
    __syncthreads();  // protect Ks/Vs/Qs(first iter) from prior readers
    // stage K,V tile: thread -> (jj = tid>>2, 16 dims at (tid&3)*16)
    {
      int jj = tid >> 2, dseg = (tid & 3) * 16;
      const __hip_bfloat16* kp = qkv + base + H_ + (size_t)(j0 + jj) * (3 * H_) + dseg;
      const __hip_bfloat16* vp = kp + H_;
      uint4 ku0 = *(const uint4*)kp, ku1 = *(const uint4*)(kp + 8);
      uint4 vu0 = *(const uint4*)vp, vu1 = *(const uint4*)(vp + 8);
      const unsigned* ka = (const unsigned*)&ku0;
      const unsigned* kb2 = (const unsigned*)&ku1;
      const unsigned* va = (const unsigned*)&vu0;
      const unsigned* vb = (const unsigned*)&vu1;
      #pragma unroll
      for (int i = 0; i < 4; i++) {
        Ks[jj][dseg + 2 * i + 0] = __uint_as_float(ka[i] << 16);
        Ks[jj][dseg + 2 * i + 1] = __uint_as_float(ka[i] & 0xffff0000u);
        Ks[jj][dseg + 8 + 2 * i + 0] = __uint_as_float(kb2[i] << 16);
        Ks[jj][dseg + 8 + 2 * i + 1] = __uint_as_float(kb2[i] & 0xffff0000u);
        Vs[jj][dseg + 2 * i + 0] = __uint_as_float(va[i] << 16);
        Vs[jj][dseg + 2 * i + 1] = __uint_as_float(va[i] & 0xffff0000u);
        Vs[jj][dseg + 8 + 2 * i + 0] = __uint_as_float(vb[i] << 16);
        Vs[jj][dseg + 8 + 2 * i + 1] = __uint_as_float(vb[i] & 0xffff0000u);
      }
    }
    __syncthreads();

    // scores: thread (r,c) handles j_local = c + 8*jj2
    float sreg[8];
    float pm = -INFINITY;
    #pragma unroll
    for (int jj2 = 0; jj2 < 8; jj2++) {
      int jl = c + 8 * jj2;
      float s = 0.f;
      const float4* qv = (const float4*)(&Qs[r][0]);
      const float4* kv = (const float4*)(&Ks[jl][0]);
      #pragma unroll
      for (int d4 = 0; d4 < 16; d4++) {
        float4 qq = qv[d4], kk = kv[d4];
        s += qq.x * kk.x + qq.y * kk.y + qq.z * kk.z + qq.w * kk.w;
      }
      int j = j0 + jl;
      if (j > i_row || (i_row >= sp && j < sp))
        s = -1e9f;
      else
        s += slope * (float)(j - i_row);  // alibi = -slope*(i-j)
      sreg[jj2] = s;
      pm = fmaxf(pm, s);
    }
    pmax[r][c] = pm;
    __syncthreads();
    if (tid < 32) {
      float tm = rowm[tid];
      #pragma unroll
      for (int cc = 0; cc < 8; cc++) tm = fmaxf(tm, pmax[tid][cc]);
      float al = __expf(rowm[tid] - tm);  // -inf -> 0, never NaN (tm >= -1e9)
      rowm[tid] = tm;
      alpha_s[tid] = al;
    }
    __syncthreads();
    float newm = rowm[r];
    float psl = 0.f;
    #pragma unroll
    for (int jj2 = 0; jj2 < 8; jj2++) {
      float p = __expf(sreg[jj2] - newm);
      Sc[r][c + 8 * jj2] = p;
      psl += p;
    }
    psum[r][c] = psl;
    __syncthreads();
    if (tid < 32) {
      float s2 = 0.f;
      #pragma unroll
      for (int cc = 0; cc < 8; cc++) s2 += psum[tid][cc];
      rowl[tid] = rowl[tid] * alpha_s[tid] + s2;
    }
    // rescale + PV
    float al_r = alpha_s[r];
    #pragma unroll
    for (int i = 0; i < 8; i++) o[i] *= al_r;
    for (int jj = 0; jj < 64; jj++) {
      float p = Sc[r][jj];
      const float4* vv = (const float4*)(&Vs[jj][c * 8]);
      float4 v0 = vv[0], v1 = vv[1];
      o[0] += p * v0.x; o[1] += p * v0.y; o[2] += p * v0.z; o[3] += p * v0.w;
      o[4] += p * v1.x; o[5] += p * v1.y; o[6] += p * v1.z; o[7] += p * v1.w;
    }
  }
  __syncthreads();
  float linv = 1.0f / rowl[r];
  __hip_bfloat16* op = out + ((size_t)b * S_ + i_row) * H_ + hh * DH_ + c * 8;
  #pragma unroll
  for (int i = 0; i < 8; i++) op[i] = __float2bfloat16(o[i] * linv);
}

// ---------------- launch ----------------
extern "C" void kernel_launch(void* const* d_in, const int* in_sizes, int n_in,
                              void* d_out, int out_size, void* d_ws, size_t ws_size,
                              hipStream_t stream) {
  const int* ids = (const int*)d_in[0];
  const int* sp = (const int*)d_in[1];
  const float* emb = (const float*)d_in[2];
  const float* ln1_g = (const float*)d_in[3];
  const float* ln1_b = (const float*)d_in[4];
  const float* Wqkv = (const float*)d_in[5];
  const float* bqkv = (const float*)d_in[6];
  const float* Wo = (const float*)d_in[7];
  const float* bo = (const float*)d_in[8];
  const float* ln2_g = (const float*)d_in[9];
  const float* ln2_b = (const float*)d_in[10];
  const float* Wfc = (const float*)d_in[11];
  const float* bfc = (const float*)d_in[12];
  const float* Wproj = (const float*)d_in[13];
  const float* bproj = (const float*)d_in[14];
  const float* lnf_g = (const float*)d_in[15];
  const float* lnf_b = (const float*)d_in[16];

  char* p = (char*)d_ws;
  __hip_bfloat16* WqkvT = (__hip_bfloat16*)p; p += (size_t)NL_ * 3 * H_ * H_ * 2;
  __hip_bfloat16* WoT = (__hip_bfloat16*)p;   p += (size_t)NL_ * H_ * H_ * 2;
  __hip_bfloat16* WfcT = (__hip_bfloat16*)p;  p += (size_t)NL_ * F_ * H_ * 2;
  __hip_bfloat16* WprojT = (__hip_bfloat16*)p; p += (size_t)NL_ * H_ * F_ * 2;
  __hip_bfloat16* embb = (__hip_bfloat16*)p;  p += (size_t)V_ * H_ * 2;
  float* x = (float*)p;                        p += (size_t)B_ * S_ * H_ * 4;
  __hip_bfloat16* h = (__hip_bfloat16*)p;     p += (size_t)B_ * S_ * H_ * 2;
  __hip_bfloat16* qkv = (__hip_bfloat16*)p;   p += (size_t)B_ * S_ * 3 * H_ * 2;
  __hip_bfloat16* g = (__hip_bfloat16*)p;     p += (size_t)B_ * S_ * F_ * 2;

  dim3 tb(32, 8);
  transpose_cvt<<<dim3(3 * H_ / 32, H_ / 32, NL_), tb, 0, stream>>>(Wqkv, WqkvT, H_, 3 * H_);
  transpose_cvt<<<dim3(H_ / 32, H_ / 32, NL_), tb, 0, stream>>>(Wo, WoT, H_, H_);
  transpose_cvt<<<dim3(F_ / 32, H_ / 32, NL_), tb, 0, stream>>>(Wfc, WfcT, H_, F_);
  transpose_cvt<<<dim3(H_ / 32, F_ / 32, NL_), tb, 0, stream>>>(Wproj, WprojT, F_, H_);
  cvt_bf16<<<V_ * H_ / 1024, 256, 0, stream>>>(emb, embb);
  embed_k<<<B_ * S_, 256, 0, stream>>>(ids, emb, x);

  const int M = B_ * S_;
  for (int l = 0; l < NL_; l++) {
    ln_k<<<M, 256, 0, stream>>>(x, ln1_g + l * H_, ln1_b + l * H_, h);
    gemm_bt<0><<<dim3(3 * H_ / 128, M / 128), 256, 0, stream>>>(
        h, WqkvT + (size_t)l * 3 * H_ * H_, bqkv + l * 3 * H_, qkv, M, 3 * H_, H_);
    attn_k<<<B_ * NH_ * (S_ / 32), 256, 0, stream>>>(qkv, sp, h);
    gemm_bt<3><<<dim3(H_ / 128, M / 128), 256, 0, stream>>>(
        h, WoT + (size_t)l * H_ * H_, bo + l * H_, x, M, H_, H_);
    ln_k<<<M, 256, 0, stream>>>(x, ln2_g + l * H_, ln2_b + l * H_, h);
    gemm_bt<1><<<dim3(F_ / 128, M / 128), 256, 0, stream>>>(
        h, WfcT + (size_t)l * F_ * H_, bfc + l * F_, g, M, F_, H_);
    gemm_bt<3><<<dim3(H_ / 128, M / 128), 256, 0, stream>>>(
        g, WprojT + (size_t)l * H_ * F_, bproj + l * H_, x, M, H_, F_);
  }
  ln_k<<<M, 256, 0, stream>>>(x, lnf_g, lnf_b, h);
  gemm_bt<2><<<dim3(V_ / 128, M / 128), 256, 0, stream>>>(h, embb, nullptr, d_out, M, V_, H_);
}

// Round 2
// 4251.038 us; speedup vs baseline: 1.8211x; 1.8211x over previous
//
#include <hip/hip_runtime.h>
#include <hip/hip_bf16.h>

#define B_  16
#define S_  512
#define V_  512
#define H_  1024
#define NL_ 8
#define NH_ 16
#define DH_ 64
#define F_  4096

typedef __attribute__((ext_vector_type(8))) short bf16x8;
typedef __attribute__((ext_vector_type(4))) float f32x4;

__device__ __forceinline__ float gelu_tanh(float x) {
  float x3 = x * x * x;
  return 0.5f * x * (1.0f + tanhf(0.7978845608028654f * (x + 0.044715f * x3)));
}

// async global->LDS, 16B per lane; lds dest must be wave-uniform (lane i lands at l + i*16)
__device__ __forceinline__ void gload_lds16(const void* g, void* l) {
  __builtin_amdgcn_global_load_lds(
      (const __attribute__((address_space(1))) unsigned int*)(unsigned long long)g,
      (__attribute__((address_space(3))) unsigned int*)(unsigned long long)l,
      16, 0, 0);
}

// ---------------- weight transpose + fp32->bf16 ----------------
// W: (L, K, N) fp32  ->  WT: (L, N, K) bf16
__global__ __launch_bounds__(256) void transpose_cvt(const float* __restrict__ W,
                                                     __hip_bfloat16* __restrict__ WT,
                                                     int K, int N) {
  __shared__ float tile[32][33];
  int l = blockIdx.z;
  int k0 = blockIdx.y * 32, n0 = blockIdx.x * 32;
  const float* Wl = W + (size_t)l * K * N;
  __hip_bfloat16* WTl = WT + (size_t)l * N * K;
  int tx = threadIdx.x, ty = threadIdx.y;
  #pragma unroll
  for (int i = 0; i < 32; i += 8)
    tile[ty + i][tx] = Wl[(size_t)(k0 + ty + i) * N + n0 + tx];
  __syncthreads();
  #pragma unroll
  for (int i = 0; i < 32; i += 8)
    WTl[(size_t)(n0 + ty + i) * K + k0 + tx] = __float2bfloat16(tile[tx][ty + i]);
}

__global__ __launch_bounds__(256) void cvt_bf16(const float* __restrict__ in,
                                                __hip_bfloat16* __restrict__ out) {
  int i = (blockIdx.x * 256 + threadIdx.x) * 4;
  float4 v = *(const float4*)(in + i);
  out[i + 0] = __float2bfloat16(v.x);
  out[i + 1] = __float2bfloat16(v.y);
  out[i + 2] = __float2bfloat16(v.z);
  out[i + 3] = __float2bfloat16(v.w);
}

// ---------------- embedding ----------------
__global__ __launch_bounds__(256) void embed_k(const int* __restrict__ ids,
                                               const float* __restrict__ emb,
                                               float* __restrict__ x) {
  int t = blockIdx.x;
  int v = ids[t];
  int d = threadIdx.x * 4;
  float4 val = *(const float4*)(emb + (size_t)v * H_ + d);
  *(float4*)(x + (size_t)t * H_ + d) = val;
}

// ---------------- layernorm (fp32 in, bf16 out) ----------------
__global__ __launch_bounds__(256) void ln_k(const float* __restrict__ x,
                                            const float* __restrict__ g,
                                            const float* __restrict__ b,
                                            __hip_bfloat16* __restrict__ out) {
  int t = blockIdx.x;
  const float* xr = x + (size_t)t * H_;
  float4 v = ((const float4*)xr)[threadIdx.x];
  float s = v.x + v.y + v.z + v.w;
  float q = v.x * v.x + v.y * v.y + v.z * v.z + v.w * v.w;
  #pragma unroll
  for (int off = 32; off; off >>= 1) {
    s += __shfl_down(s, off);
    q += __shfl_down(q, off);
  }
  __shared__ float ps[4], pq[4];
  __shared__ float mu_s, rstd_s;
  int wave = threadIdx.x >> 6, lane = threadIdx.x & 63;
  if (lane == 0) { ps[wave] = s; pq[wave] = q; }
  __syncthreads();
  if (threadIdx.x == 0) {
    float S = ps[0] + ps[1] + ps[2] + ps[3];
    float Q = pq[0] + pq[1] + pq[2] + pq[3];
    float mu = S * (1.0f / H_);
    float var = Q * (1.0f / H_) - mu * mu;
    mu_s = mu;
    rstd_s = rsqrtf(var + 1e-5f);
  }
  __syncthreads();
  float mu = mu_s, rstd = rstd_s;
  int d = threadIdx.x * 4;
  float4 gv = ((const float4*)g)[threadIdx.x];
  float4 bv = ((const float4*)b)[threadIdx.x];
  __hip_bfloat16* op = out + (size_t)t * H_ + d;
  op[0] = __float2bfloat16((v.x - mu) * rstd * gv.x + bv.x);
  op[1] = __float2bfloat16((v.y - mu) * rstd * gv.y + bv.y);
  op[2] = __float2bfloat16((v.z - mu) * rstd * gv.z + bv.z);
  op[3] = __float2bfloat16((v.w - mu) * rstd * gv.w + bv.w);
}

// ---------------- GEMM: C = A(MxK) * BT(NxK)^T  [bf16 MFMA, global_load_lds] ----
// MODE 0: bf16 out + bias; 1: bf16 out + bias + gelu; 2: fp32 out (+bias if set);
// MODE 3: fp32 residual add (C += A*B + bias)
template <int MODE>
__global__ __launch_bounds__(256) void gemm_bt(const __hip_bfloat16* __restrict__ A,
                                               const __hip_bfloat16* __restrict__ BT,
                                               const float* __restrict__ bias,
                                               void* __restrict__ Cv,
                                               int M, int N, int K) {
  constexpr int BM = 128, BN = 128, BK = 32;
  __shared__ __hip_bfloat16 As[BM * BK];  // unpadded: row = 32 bf16 = 64B (global_load_lds layout)
  __shared__ __hip_bfloat16 Bs[BN * BK];
  const int tid = threadIdx.x;
  const int m0 = blockIdx.y * BM, n0 = blockIdx.x * BN;
  const int wave = tid >> 6, lane = tid & 63;
  const int wr = (wave >> 1) * 64, wc = (wave & 1) * 64;
  const int quad = lane >> 4, l16 = lane & 15;

  f32x4 acc[4][4];
  #pragma unroll
  for (int i = 0; i < 4; i++)
    #pragma unroll
    for (int j = 0; j < 4; j++) acc[i][j] = (f32x4){0.f, 0.f, 0.f, 0.f};

  // each wave stages 32 rows of A and B per k-step: 2 calls x (16 rows, lane -> row lane>>2, chunk lane&3)
  const int srow = (lane >> 2), scol = (lane & 3) * 8;
  const __hip_bfloat16* agp0 = A + (size_t)(m0 + wave * 32 + srow) * K + scol;
  const __hip_bfloat16* agp1 = agp0 + (size_t)16 * K;
  const __hip_bfloat16* bgp0 = BT + (size_t)(n0 + wave * 32 + srow) * K + scol;
  const __hip_bfloat16* bgp1 = bgp0 + (size_t)16 * K;
  __hip_bfloat16* al0 = As + (wave * 32) * 32;
  __hip_bfloat16* al1 = As + (wave * 32 + 16) * 32;
  __hip_bfloat16* bl0 = Bs + (wave * 32) * 32;
  __hip_bfloat16* bl1 = Bs + (wave * 32 + 16) * 32;

  for (int k0 = 0; k0 < K; k0 += BK) {
    __syncthreads();  // prior iter's frag reads done before overwrite
    gload_lds16(agp0, al0);
    gload_lds16(agp1, al1);
    gload_lds16(bgp0, bl0);
    gload_lds16(bgp1, bl1);
    agp0 += BK; agp1 += BK; bgp0 += BK; bgp1 += BK;
    __syncthreads();  // compiler emits vmcnt(0) drain before barrier -> LDS data ready
    bf16x8 af[4], bfr[4];
    #pragma unroll
    for (int mt = 0; mt < 4; mt++)
      af[mt] = *(const bf16x8*)(&As[(wr + mt * 16 + l16) * 32 + quad * 8]);
    #pragma unroll
    for (int nt = 0; nt < 4; nt++)
      bfr[nt] = *(const bf16x8*)(&Bs[(wc + nt * 16 + l16) * 32 + quad * 8]);
    #pragma unroll
    for (int mt = 0; mt < 4; mt++)
      #pragma unroll
      for (int nt = 0; nt < 4; nt++)
        acc[mt][nt] = __builtin_amdgcn_mfma_f32_16x16x32_bf16(af[mt], bfr[nt], acc[mt][nt], 0, 0, 0);
  }

  #pragma unroll
  for (int mt = 0; mt < 4; mt++) {
    #pragma unroll
    for (int nt = 0; nt < 4; nt++) {
      int col = n0 + wc + nt * 16 + l16;
      float bv = bias ? bias[col] : 0.f;
      #pragma unroll
      for (int rr = 0; rr < 4; rr++) {
        int row = m0 + wr + mt * 16 + quad * 4 + rr;
        float v = acc[mt][nt][rr] + bv;
        if constexpr (MODE == 0) {
          ((__hip_bfloat16*)Cv)[(size_t)row * N + col] = __float2bfloat16(v);
        } else if constexpr (MODE == 1) {
          ((__hip_bfloat16*)Cv)[(size_t)row * N + col] = __float2bfloat16(gelu_tanh(v));
        } else if constexpr (MODE == 2) {
          ((float*)Cv)[(size_t)row * N + col] = v;
        } else {
          ((float*)Cv)[(size_t)row * N + col] += v;
        }
      }
    }
  }
}

// ---------------- fused MFMA flash attention ----------------
// qkv: (B*S, 3H) bf16; out: (B*S, H) bf16.
// Block = 256 thr (4 waves); wave w owns q rows [i0 + w*16, +16). One block per (b, head, 64-row q tile).
__global__ __launch_bounds__(256) void attn_mfma(const __hip_bfloat16* __restrict__ qkv,
                                                 const int* __restrict__ split_positions,
                                                 __hip_bfloat16* __restrict__ out) {
  constexpr int LD = 66;  // stride pad: conflict-free b128 fragment reads
  __shared__ __hip_bfloat16 Qs[64 * LD];
  __shared__ __hip_bfloat16 Ks[64 * LD];
  __shared__ __hip_bfloat16 Vt[64 * LD];  // transposed: Vt[dh][key]
  __shared__ __hip_bfloat16 Ps[64 * LD];  // P round-trip, wave-private 16-row slabs

  const int bid = blockIdx.x;
  const int qt = bid & 7;          // S/64 = 8 q-tiles
  const int hh = (bid >> 3) & 15;
  const int b = bid >> 7;
  const int sp = split_positions[b];
  const int i0 = qt * 64;
  const int tid = threadIdx.x;
  const int wave = tid >> 6, lane = tid & 63;
  const int quad = lane >> 4, l16 = lane & 15;
  const float slope = exp2f(-0.5f * (float)(hh + 1));
  const size_t rs = 3 * H_;
  const size_t base = (size_t)b * S_ * rs + (size_t)hh * DH_;

  // stage Q tile (64 x 64), row-major
  {
    int r = tid >> 2, d = (tid & 3) * 16;
    const __hip_bfloat16* qp = qkv + base + (size_t)(i0 + r) * rs + d;
    uint4 u0 = *(const uint4*)qp;
    uint4 u1 = *(const uint4*)(qp + 8);
    *(uint4*)&Qs[r * LD + d] = u0;
    *(uint4*)&Qs[r * LD + d + 8] = u1;
  }

  float m_i[4], l_i[4];
  f32x4 acc_o[4];
  #pragma unroll
  for (int rr = 0; rr < 4; rr++) { m_i[rr] = -INFINITY; l_i[rr] = 0.f; }
  #pragma unroll
  for (int nt = 0; nt < 4; nt++) acc_o[nt] = (f32x4){0.f, 0.f, 0.f, 0.f};

  const int i_row_base = i0 + wave * 16 + quad * 4;
  const int ktiles = qt + 1;

  for (int kt = 0; kt < ktiles; kt++) {
    const int j0 = kt * 64;
    __syncthreads();  // prev-iter readers done (also orders Q staging before first read)
    // stage K (row-major) and V (transposed) tiles
    {
      int r = tid >> 2, d = (tid & 3) * 16;
      const __hip_bfloat16* kp = qkv + base + H_ + (size_t)(j0 + r) * rs + d;
      uint4 k0v = *(const uint4*)kp;
      uint4 k1v = *(const uint4*)(kp + 8);
      *(uint4*)&Ks[r * LD + d] = k0v;
      *(uint4*)&Ks[r * LD + d + 8] = k1v;
      const __hip_bfloat16* vp = kp + H_;
      uint4 v0 = *(const uint4*)vp;
      uint4 v1 = *(const uint4*)(vp + 8);
      const __hip_bfloat16* vv0 = (const __hip_bfloat16*)&v0;
      const __hip_bfloat16* vv1 = (const __hip_bfloat16*)&v1;
      #pragma unroll
      for (int i = 0; i < 8; i++) Vt[(d + i) * LD + r] = vv0[i];
      #pragma unroll
      for (int i = 0; i < 8; i++) Vt[(d + 8 + i) * LD + r] = vv1[i];
    }
    __syncthreads();

    // S = Q K^T for this wave's 16 rows x 64 keys
    f32x4 acc_s[4];
    #pragma unroll
    for (int nt = 0; nt < 4; nt++) acc_s[nt] = (f32x4){0.f, 0.f, 0.f, 0.f};
    bf16x8 aq0 = *(const bf16x8*)&Qs[(wave * 16 + l16) * LD + quad * 8];
    bf16x8 aq1 = *(const bf16x8*)&Qs[(wave * 16 + l16) * LD + 32 + quad * 8];
    #pragma unroll
    for (int nt = 0; nt < 4; nt++) {
      bf16x8 bk0 = *(const bf16x8*)&Ks[(nt * 16 + l16) * LD + quad * 8];
      bf16x8 bk1 = *(const bf16x8*)&Ks[(nt * 16 + l16) * LD + 32 + quad * 8];
      acc_s[nt] = __builtin_amdgcn_mfma_f32_16x16x32_bf16(aq0, bk0, acc_s[nt], 0, 0, 0);
      acc_s[nt] = __builtin_amdgcn_mfma_f32_16x16x32_bf16(aq1, bk1, acc_s[nt], 0, 0, 0);
    }

    // scale + alibi + mask; per-row tile max
    float tm[4] = {-INFINITY, -INFINITY, -INFINITY, -INFINITY};
    #pragma unroll
    for (int nt = 0; nt < 4; nt++) {
      int j = j0 + nt * 16 + l16;
      #pragma unroll
      for (int rr = 0; rr < 4; rr++) {
        int i_row = i_row_base + rr;
        float s = acc_s[nt][rr] * 0.125f + slope * (float)(j - i_row);
        bool masked = (j > i_row) || (i_row >= sp && j < sp);
        s = masked ? -1e9f : s;
        acc_s[nt][rr] = s;
        tm[rr] = fmaxf(tm[rr], s);
      }
    }
    #pragma unroll
    for (int rr = 0; rr < 4; rr++) {
      #pragma unroll
      for (int off = 1; off < 16; off <<= 1) tm[rr] = fmaxf(tm[rr], __shfl_xor(tm[rr], off));
    }

    float alpha[4], psum[4];
    #pragma unroll
    for (int rr = 0; rr < 4; rr++) {
      float mn = fmaxf(m_i[rr], tm[rr]);
      alpha[rr] = __expf(m_i[rr] - mn);  // m_i=-inf, mn finite -> 0 (no NaN: mn >= -1e9)
      m_i[rr] = mn;
      psum[rr] = 0.f;
    }
    #pragma unroll
    for (int nt = 0; nt < 4; nt++) {
      #pragma unroll
      for (int rr = 0; rr < 4; rr++) {
        float p = __expf(acc_s[nt][rr] - m_i[rr]);
        acc_s[nt][rr] = p;
        psum[rr] += p;
      }
    }
    #pragma unroll
    for (int rr = 0; rr < 4; rr++) {
      #pragma unroll
      for (int off = 1; off < 16; off <<= 1) psum[rr] += __shfl_xor(psum[rr], off);
      l_i[rr] = l_i[rr] * alpha[rr] + psum[rr];
    }

    // P (C-layout) -> LDS (row-major, wave-private slab) -> A-layout frags
    #pragma unroll
    for (int nt = 0; nt < 4; nt++)
      #pragma unroll
      for (int rr = 0; rr < 4; rr++)
        Ps[(wave * 16 + quad * 4 + rr) * LD + nt * 16 + l16] = __float2bfloat16(acc_s[nt][rr]);

    #pragma unroll
    for (int nt = 0; nt < 4; nt++) {
      #pragma unroll
      for (int rr = 0; rr < 4; rr++) acc_o[nt][rr] *= alpha[rr];
    }
    // wave-private write->read: compiler inserts lgkmcnt wait, no barrier needed
    bf16x8 ap0 = *(const bf16x8*)&Ps[(wave * 16 + l16) * LD + quad * 8];
    bf16x8 ap1 = *(const bf16x8*)&Ps[(wave * 16 + l16) * LD + 32 + quad * 8];
    #pragma unroll
    for (int nt = 0; nt < 4; nt++) {
      bf16x8 bv0 = *(const bf16x8*)&Vt[(nt * 16 + l16) * LD + quad * 8];
      bf16x8 bv1 = *(const bf16x8*)&Vt[(nt * 16 + l16) * LD + 32 + quad * 8];
      acc_o[nt] = __builtin_amdgcn_mfma_f32_16x16x32_bf16(ap0, bv0, acc_o[nt], 0, 0, 0);
      acc_o[nt] = __builtin_amdgcn_mfma_f32_16x16x32_bf16(ap1, bv1, acc_o[nt], 0, 0, 0);
    }
  }

  float inv[4];
  #pragma unroll
  for (int rr = 0; rr < 4; rr++) inv[rr] = 1.0f / l_i[rr];
  #pragma unroll
  for (int nt = 0; nt < 4; nt++) {
    #pragma unroll
    for (int rr = 0; rr < 4; rr++) {
      size_t row = (size_t)b * S_ + i_row_base + rr;
      out[row * H_ + hh * DH_ + nt * 16 + l16] = __float2bfloat16(acc_o[nt][rr] * inv[rr]);
    }
  }
}

// ---------------- launch ----------------
extern "C" void kernel_launch(void* const* d_in, const int* in_sizes, int n_in,
                              void* d_out, int out_size, void* d_ws, size_t ws_size,
                              hipStream_t stream) {
  const int* ids = (const int*)d_in[0];
  const int* sp = (const int*)d_in[1];
  const float* emb = (const float*)d_in[2];
  const float* ln1_g = (const float*)d_in[3];
  const float* ln1_b = (const float*)d_in[4];
  const float* Wqkv = (const float*)d_in[5];
  const float* bqkv = (const float*)d_in[6];
  const float* Wo = (const float*)d_in[7];
  const float* bo = (const float*)d_in[8];
  const float* ln2_g = (const float*)d_in[9];
  const float* ln2_b = (const float*)d_in[10];
  const float* Wfc = (const float*)d_in[11];
  const float* bfc = (const float*)d_in[12];
  const float* Wproj = (const float*)d_in[13];
  const float* bproj = (const float*)d_in[14];
  const float* lnf_g = (const float*)d_in[15];
  const float* lnf_b = (const float*)d_in[16];

  char* p = (char*)d_ws;
  __hip_bfloat16* WqkvT = (__hip_bfloat16*)p; p += (size_t)NL_ * 3 * H_ * H_ * 2;
  __hip_bfloat16* WoT = (__hip_bfloat16*)p;   p += (size_t)NL_ * H_ * H_ * 2;
  __hip_bfloat16* WfcT = (__hip_bfloat16*)p;  p += (size_t)NL_ * F_ * H_ * 2;
  __hip_bfloat16* WprojT = (__hip_bfloat16*)p; p += (size_t)NL_ * H_ * F_ * 2;
  __hip_bfloat16* embb = (__hip_bfloat16*)p;  p += (size_t)V_ * H_ * 2;
  float* x = (float*)p;                        p += (size_t)B_ * S_ * H_ * 4;
  __hip_bfloat16* h = (__hip_bfloat16*)p;     p += (size_t)B_ * S_ * H_ * 2;
  __hip_bfloat16* qkv = (__hip_bfloat16*)p;   p += (size_t)B_ * S_ * 3 * H_ * 2;
  __hip_bfloat16* g = (__hip_bfloat16*)p;     p += (size_t)B_ * S_ * F_ * 2;

  dim3 tb(32, 8);
  transpose_cvt<<<dim3(3 * H_ / 32, H_ / 32, NL_), tb, 0, stream>>>(Wqkv, WqkvT, H_, 3 * H_);
  transpose_cvt<<<dim3(H_ / 32, H_ / 32, NL_), tb, 0, stream>>>(Wo, WoT, H_, H_);
  transpose_cvt<<<dim3(F_ / 32, H_ / 32, NL_), tb, 0, stream>>>(Wfc, WfcT, H_, F_);
  transpose_cvt<<<dim3(H_ / 32, F_ / 32, NL_), tb, 0, stream>>>(Wproj, WprojT, F_, H_);
  cvt_bf16<<<V_ * H_ / 1024, 256, 0, stream>>>(emb, embb);
  embed_k<<<B_ * S_, 256, 0, stream>>>(ids, emb, x);

  const int M = B_ * S_;
  for (int l = 0; l < NL_; l++) {
    ln_k<<<M, 256, 0, stream>>>(x, ln1_g + l * H_, ln1_b + l * H_, h);
    gemm_bt<0><<<dim3(3 * H_ / 128, M / 128), 256, 0, stream>>>(
        h, WqkvT + (size_t)l * 3 * H_ * H_, bqkv + l * 3 * H_, qkv, M, 3 * H_, H_);
    attn_mfma<<<B_ * NH_ * (S_ / 64), 256, 0, stream>>>(qkv, sp, h);
    gemm_bt<3><<<dim3(H_ / 128, M / 128), 256, 0, stream>>>(
        h, WoT + (size_t)l * H_ * H_, bo + l * H_, x, M, H_, H_);
    ln_k<<<M, 256, 0, stream>>>(x, ln2_g + l * H_, ln2_b + l * H_, h);
    gemm_bt<1><<<dim3(F_ / 128, M / 128), 256, 0, stream>>>(
        h, WfcT + (size_t)l * F_ * H_, bfc + l * F_, g, M, F_, H_);
    gemm_bt<3><<<dim3(H_ / 128, M / 128), 256, 0, stream>>>(
        g, WprojT + (size_t)l * H_ * F_, bproj + l * H_, x, M, H_, F_);
  }
  ln_k<<<M, 256, 0, stream>>>(x, lnf_g, lnf_b, h);
  gemm_bt<2><<<dim3(V_ / 128, M / 128), 256, 0, stream>>>(h, embb, nullptr, d_out, M, V_, H_);
}

// Round 3
// 3982.570 us; speedup vs baseline: 1.9439x; 1.0674x over previous
//
#include <hip/hip_runtime.h>
#include <hip/hip_bf16.h>

#define B_  16
#define S_  512
#define V_  512
#define H_  1024
#define NL_ 8
#define NH_ 16
#define DH_ 64
#define F_  4096

typedef __attribute__((ext_vector_type(8))) short bf16x8;
typedef __attribute__((ext_vector_type(4))) float f32x4;

__device__ __forceinline__ float gelu_tanh(float x) {
  float x3 = x * x * x;
  return 0.5f * x * (1.0f + tanhf(0.7978845608028654f * (x + 0.044715f * x3)));
}

// async global->LDS, 16B per lane; lds dest is wave-uniform base (lane i lands at base + i*16)
__device__ __forceinline__ void gload_lds16(const void* g, void* l) {
  __builtin_amdgcn_global_load_lds(
      (const __attribute__((address_space(1))) unsigned int*)(unsigned long long)g,
      (__attribute__((address_space(3))) unsigned int*)(unsigned long long)l,
      16, 0, 0);
}

// ---------------- weight transpose + fp32->bf16 ----------------
__global__ __launch_bounds__(256) void transpose_cvt(const float* __restrict__ W,
                                                     __hip_bfloat16* __restrict__ WT,
                                                     int K, int N) {
  __shared__ float tile[32][33];
  int l = blockIdx.z;
  int k0 = blockIdx.y * 32, n0 = blockIdx.x * 32;
  const float* Wl = W + (size_t)l * K * N;
  __hip_bfloat16* WTl = WT + (size_t)l * N * K;
  int tx = threadIdx.x, ty = threadIdx.y;
  #pragma unroll
  for (int i = 0; i < 32; i += 8)
    tile[ty + i][tx] = Wl[(size_t)(k0 + ty + i) * N + n0 + tx];
  __syncthreads();
  #pragma unroll
  for (int i = 0; i < 32; i += 8)
    WTl[(size_t)(n0 + ty + i) * K + k0 + tx] = __float2bfloat16(tile[tx][ty + i]);
}

__global__ __launch_bounds__(256) void cvt_bf16(const float* __restrict__ in,
                                                __hip_bfloat16* __restrict__ out) {
  int i = (blockIdx.x * 256 + threadIdx.x) * 4;
  float4 v = *(const float4*)(in + i);
  out[i + 0] = __float2bfloat16(v.x);
  out[i + 1] = __float2bfloat16(v.y);
  out[i + 2] = __float2bfloat16(v.z);
  out[i + 3] = __float2bfloat16(v.w);
}

// ---------------- embedding ----------------
__global__ __launch_bounds__(256) void embed_k(const int* __restrict__ ids,
                                               const float* __restrict__ emb,
                                               float* __restrict__ x) {
  int t = blockIdx.x;
  int v = ids[t];
  int d = threadIdx.x * 4;
  float4 val = *(const float4*)(emb + (size_t)v * H_ + d);
  *(float4*)(x + (size_t)t * H_ + d) = val;
}

// ---------------- layernorm (fp32 in, bf16 out) ----------------
__global__ __launch_bounds__(256) void ln_k(const float* __restrict__ x,
                                            const float* __restrict__ g,
                                            const float* __restrict__ b,
                                            __hip_bfloat16* __restrict__ out) {
  int t = blockIdx.x;
  const float* xr = x + (size_t)t * H_;
  float4 v = ((const float4*)xr)[threadIdx.x];
  float s = v.x + v.y + v.z + v.w;
  float q = v.x * v.x + v.y * v.y + v.z * v.z + v.w * v.w;
  #pragma unroll
  for (int off = 32; off; off >>= 1) {
    s += __shfl_down(s, off);
    q += __shfl_down(q, off);
  }
  __shared__ float ps[4], pq[4];
  __shared__ float mu_s, rstd_s;
  int wave = threadIdx.x >> 6, lane = threadIdx.x & 63;
  if (lane == 0) { ps[wave] = s; pq[wave] = q; }
  __syncthreads();
  if (threadIdx.x == 0) {
    float S = ps[0] + ps[1] + ps[2] + ps[3];
    float Q = pq[0] + pq[1] + pq[2] + pq[3];
    float mu = S * (1.0f / H_);
    float var = Q * (1.0f / H_) - mu * mu;
    mu_s = mu;
    rstd_s = rsqrtf(var + 1e-5f);
  }
  __syncthreads();
  float mu = mu_s, rstd = rstd_s;
  int d = threadIdx.x * 4;
  float4 gv = ((const float4*)g)[threadIdx.x];
  float4 bv = ((const float4*)b)[threadIdx.x];
  __hip_bfloat16* op = out + (size_t)t * H_ + d;
  op[0] = __float2bfloat16((v.x - mu) * rstd * gv.x + bv.x);
  op[1] = __float2bfloat16((v.y - mu) * rstd * gv.y + bv.y);
  op[2] = __float2bfloat16((v.z - mu) * rstd * gv.z + bv.z);
  op[3] = __float2bfloat16((v.w - mu) * rstd * gv.w + bv.w);
}

// ---------------- GEMM: C = A(MxK) * BT(NxK)^T  [bf16 MFMA, dbuf global_load_lds] ----
// MODE 0: bf16 out + bias; 1: bf16 + bias + gelu; 2: fp32 out (+bias if set);
// MODE 3: fp32 residual add (C += A*B + bias)
// MT: m-subtiles per wave (4 -> BM=128, 2 -> BM=64). 1D grid, XCD-swizzled.
template <int MODE, int MT>
__global__ __launch_bounds__(256) void gemm_bt(const __hip_bfloat16* __restrict__ A,
                                               const __hip_bfloat16* __restrict__ BT,
                                               const float* __restrict__ bias,
                                               void* __restrict__ Cv,
                                               int M, int N, int K) {
  constexpr int BM = MT * 32, BN = 128, BK = 32;
  constexpr int ACALLS = MT / 2;  // 16-row slabs of A staged per wave
  __shared__ __hip_bfloat16 As[2][BM * BK];
  __shared__ __hip_bfloat16 Bs[2][BN * BK];
  const int tid = threadIdx.x;
  const int wave = tid >> 6, lane = tid & 63;
  const int quad = lane >> 4, l16 = lane & 15;
  const int wr = (wave >> 1) * 16 * MT, wc = (wave & 1) * 64;

  // XCD-aware block swizzle: xcd = bid&7 owns an N-column group (L2-resident B)
  const int nbn = N / BN;
  int bid = blockIdx.x, m_blk, n_blk;
  if ((nbn & 7) == 0) {
    const int g = nbn >> 3;
    const int xcd = bid & 7, local = bid >> 3;
    n_blk = xcd * g + local % g;
    m_blk = local / g;
  } else {
    n_blk = bid % nbn;
    m_blk = bid / nbn;
  }
  const int m0 = m_blk * BM, n0 = n_blk * BN;

  f32x4 acc[MT][4];
  #pragma unroll
  for (int i = 0; i < MT; i++)
    #pragma unroll
    for (int j = 0; j < 4; j++) acc[i][j] = (f32x4){0.f, 0.f, 0.f, 0.f};

  // staging: lane -> (row = lane>>2, 16B chunk = lane&3); each call = 16 rows = 1KB
  const int srow = lane >> 2, scol = (lane & 3) * 8;
  const __hip_bfloat16* agp = A + (size_t)(m0 + wave * 16 * ACALLS + srow) * K + scol;
  const __hip_bfloat16* bgp = BT + (size_t)(n0 + wave * 32 + srow) * K + scol;
  const int aoff = (wave * 16 * ACALLS) * 32;
  const int boff = (wave * 32) * 32;

  auto stage = [&](int buf, int kofs) {
    #pragma unroll
    for (int c = 0; c < ACALLS; c++)
      gload_lds16(agp + (size_t)c * 16 * K + kofs, &As[buf][aoff + c * 512]);
    #pragma unroll
    for (int c = 0; c < 2; c++)
      gload_lds16(bgp + (size_t)c * 16 * K + kofs, &Bs[buf][boff + c * 512]);
  };

  stage(0, 0);
  int cur = 0;
  for (int k0 = 0; k0 < K; k0 += BK) {
    __syncthreads();  // drains vmcnt: buf[cur] staged; prior reads of buf[cur^1] done
    if (k0 + BK < K) stage(cur ^ 1, k0 + BK);  // in flight during this iter's compute
    bf16x8 af[MT], bfr[4];
    #pragma unroll
    for (int mt = 0; mt < MT; mt++)
      af[mt] = *(const bf16x8*)(&As[cur][(wr + mt * 16 + l16) * 32 + quad * 8]);
    #pragma unroll
    for (int nt = 0; nt < 4; nt++)
      bfr[nt] = *(const bf16x8*)(&Bs[cur][(wc + nt * 16 + l16) * 32 + quad * 8]);
    #pragma unroll
    for (int mt = 0; mt < MT; mt++)
      #pragma unroll
      for (int nt = 0; nt < 4; nt++)
        acc[mt][nt] = __builtin_amdgcn_mfma_f32_16x16x32_bf16(af[mt], bfr[nt], acc[mt][nt], 0, 0, 0);
    cur ^= 1;
  }

  #pragma unroll
  for (int mt = 0; mt < MT; mt++) {
    #pragma unroll
    for (int nt = 0; nt < 4; nt++) {
      int col = n0 + wc + nt * 16 + l16;
      float bv = bias ? bias[col] : 0.f;
      #pragma unroll
      for (int rr = 0; rr < 4; rr++) {
        int row = m0 + wr + mt * 16 + quad * 4 + rr;
        float v = acc[mt][nt][rr] + bv;
        if constexpr (MODE == 0) {
          ((__hip_bfloat16*)Cv)[(size_t)row * N + col] = __float2bfloat16(v);
        } else if constexpr (MODE == 1) {
          ((__hip_bfloat16*)Cv)[(size_t)row * N + col] = __float2bfloat16(gelu_tanh(v));
        } else if constexpr (MODE == 2) {
          ((float*)Cv)[(size_t)row * N + col] = v;
        } else {
          ((float*)Cv)[(size_t)row * N + col] += v;
        }
      }
    }
  }
}

// ---------------- fused MFMA flash attention ----------------
__global__ __launch_bounds__(256) void attn_mfma(const __hip_bfloat16* __restrict__ qkv,
                                                 const int* __restrict__ split_positions,
                                                 __hip_bfloat16* __restrict__ out) {
  constexpr int LD = 66;
  __shared__ __hip_bfloat16 Qs[64 * LD];
  __shared__ __hip_bfloat16 Ks[64 * LD];
  __shared__ __hip_bfloat16 Vt[64 * LD];
  __shared__ __hip_bfloat16 Ps[64 * LD];

  const int bid = blockIdx.x;
  const int qt = bid & 7;
  const int hh = (bid >> 3) & 15;
  const int b = bid >> 7;
  const int sp = split_positions[b];
  const int i0 = qt * 64;
  const int tid = threadIdx.x;
  const int wave = tid >> 6, lane = tid & 63;
  const int quad = lane >> 4, l16 = lane & 15;
  const float slope = exp2f(-0.5f * (float)(hh + 1));
  const size_t rs = 3 * H_;
  const size_t base = (size_t)b * S_ * rs + (size_t)hh * DH_;

  {
    int r = tid >> 2, d = (tid & 3) * 16;
    const __hip_bfloat16* qp = qkv + base + (size_t)(i0 + r) * rs + d;
    uint4 u0 = *(const uint4*)qp;
    uint4 u1 = *(const uint4*)(qp + 8);
    *(uint4*)&Qs[r * LD + d] = u0;
    *(uint4*)&Qs[r * LD + d + 8] = u1;
  }

  float m_i[4], l_i[4];
  f32x4 acc_o[4];
  #pragma unroll
  for (int rr = 0; rr < 4; rr++) { m_i[rr] = -INFINITY; l_i[rr] = 0.f; }
  #pragma unroll
  for (int nt = 0; nt < 4; nt++) acc_o[nt] = (f32x4){0.f, 0.f, 0.f, 0.f};

  const int i_row_base = i0 + wave * 16 + quad * 4;
  const int ktiles = qt + 1;

  for (int kt = 0; kt < ktiles; kt++) {
    const int j0 = kt * 64;
    __syncthreads();
    {
      int r = tid >> 2, d = (tid & 3) * 16;
      const __hip_bfloat16* kp = qkv + base + H_ + (size_t)(j0 + r) * rs + d;
      uint4 k0v = *(const uint4*)kp;
      uint4 k1v = *(const uint4*)(kp + 8);
      *(uint4*)&Ks[r * LD + d] = k0v;
      *(uint4*)&Ks[r * LD + d + 8] = k1v;
      const __hip_bfloat16* vp = kp + H_;
      uint4 v0 = *(const uint4*)vp;
      uint4 v1 = *(const uint4*)(vp + 8);
      const __hip_bfloat16* vv0 = (const __hip_bfloat16*)&v0;
      const __hip_bfloat16* vv1 = (const __hip_bfloat16*)&v1;
      #pragma unroll
      for (int i = 0; i < 8; i++) Vt[(d + i) * LD + r] = vv0[i];
      #pragma unroll
      for (int i = 0; i < 8; i++) Vt[(d + 8 + i) * LD + r] = vv1[i];
    }
    __syncthreads();

    f32x4 acc_s[4];
    #pragma unroll
    for (int nt = 0; nt < 4; nt++) acc_s[nt] = (f32x4){0.f, 0.f, 0.f, 0.f};
    bf16x8 aq0 = *(const bf16x8*)&Qs[(wave * 16 + l16) * LD + quad * 8];
    bf16x8 aq1 = *(const bf16x8*)&Qs[(wave * 16 + l16) * LD + 32 + quad * 8];
    #pragma unroll
    for (int nt = 0; nt < 4; nt++) {
      bf16x8 bk0 = *(const bf16x8*)&Ks[(nt * 16 + l16) * LD + quad * 8];
      bf16x8 bk1 = *(const bf16x8*)&Ks[(nt * 16 + l16) * LD + 32 + quad * 8];
      acc_s[nt] = __builtin_amdgcn_mfma_f32_16x16x32_bf16(aq0, bk0, acc_s[nt], 0, 0, 0);
      acc_s[nt] = __builtin_amdgcn_mfma_f32_16x16x32_bf16(aq1, bk1, acc_s[nt], 0, 0, 0);
    }

    float tm[4] = {-INFINITY, -INFINITY, -INFINITY, -INFINITY};
    #pragma unroll
    for (int nt = 0; nt < 4; nt++) {
      int j = j0 + nt * 16 + l16;
      #pragma unroll
      for (int rr = 0; rr < 4; rr++) {
        int i_row = i_row_base + rr;
        float s = acc_s[nt][rr] * 0.125f + slope * (float)(j - i_row);
        bool masked = (j > i_row) || (i_row >= sp && j < sp);
        s = masked ? -1e9f : s;
        acc_s[nt][rr] = s;
        tm[rr] = fmaxf(tm[rr], s);
      }
    }
    #pragma unroll
    for (int rr = 0; rr < 4; rr++) {
      #pragma unroll
      for (int off = 1; off < 16; off <<= 1) tm[rr] = fmaxf(tm[rr], __shfl_xor(tm[rr], off));
    }

    float alpha[4], psum[4];
    #pragma unroll
    for (int rr = 0; rr < 4; rr++) {
      float mn = fmaxf(m_i[rr], tm[rr]);
      alpha[rr] = __expf(m_i[rr] - mn);
      m_i[rr] = mn;
      psum[rr] = 0.f;
    }
    #pragma unroll
    for (int nt = 0; nt < 4; nt++) {
      #pragma unroll
      for (int rr = 0; rr < 4; rr++) {
        float p = __expf(acc_s[nt][rr] - m_i[rr]);
        acc_s[nt][rr] = p;
        psum[rr] += p;
      }
    }
    #pragma unroll
    for (int rr = 0; rr < 4; rr++) {
      #pragma unroll
      for (int off = 1; off < 16; off <<= 1) psum[rr] += __shfl_xor(psum[rr], off);
      l_i[rr] = l_i[rr] * alpha[rr] + psum[rr];
    }

    #pragma unroll
    for (int nt = 0; nt < 4; nt++)
      #pragma unroll
      for (int rr = 0; rr < 4; rr++)
        Ps[(wave * 16 + quad * 4 + rr) * LD + nt * 16 + l16] = __float2bfloat16(acc_s[nt][rr]);

    #pragma unroll
    for (int nt = 0; nt < 4; nt++) {
      #pragma unroll
      for (int rr = 0; rr < 4; rr++) acc_o[nt][rr] *= alpha[rr];
    }
    bf16x8 ap0 = *(const bf16x8*)&Ps[(wave * 16 + l16) * LD + quad * 8];
    bf16x8 ap1 = *(const bf16x8*)&Ps[(wave * 16 + l16) * LD + 32 + quad * 8];
    #pragma unroll
    for (int nt = 0; nt < 4; nt++) {
      bf16x8 bv0 = *(const bf16x8*)&Vt[(nt * 16 + l16) * LD + quad * 8];
      bf16x8 bv1 = *(const bf16x8*)&Vt[(nt * 16 + l16) * LD + 32 + quad * 8];
      acc_o[nt] = __builtin_amdgcn_mfma_f32_16x16x32_bf16(ap0, bv0, acc_o[nt], 0, 0, 0);
      acc_o[nt] = __builtin_amdgcn_mfma_f32_16x16x32_bf16(ap1, bv1, acc_o[nt], 0, 0, 0);
    }
  }

  float inv[4];
  #pragma unroll
  for (int rr = 0; rr < 4; rr++) inv[rr] = 1.0f / l_i[rr];
  #pragma unroll
  for (int nt = 0; nt < 4; nt++) {
    #pragma unroll
    for (int rr = 0; rr < 4; rr++) {
      size_t row = (size_t)b * S_ + i_row_base + rr;
      out[row * H_ + hh * DH_ + nt * 16 + l16] = __float2bfloat16(acc_o[nt][rr] * inv[rr]);
    }
  }
}

// ---------------- launch ----------------
extern "C" void kernel_launch(void* const* d_in, const int* in_sizes, int n_in,
                              void* d_out, int out_size, void* d_ws, size_t ws_size,
                              hipStream_t stream) {
  const int* ids = (const int*)d_in[0];
  const int* sp = (const int*)d_in[1];
  const float* emb = (const float*)d_in[2];
  const float* ln1_g = (const float*)d_in[3];
  const float* ln1_b = (const float*)d_in[4];
  const float* Wqkv = (const float*)d_in[5];
  const float* bqkv = (const float*)d_in[6];
  const float* Wo = (const float*)d_in[7];
  const float* bo = (const float*)d_in[8];
  const float* ln2_g = (const float*)d_in[9];
  const float* ln2_b = (const float*)d_in[10];
  const float* Wfc = (const float*)d_in[11];
  const float* bfc = (const float*)d_in[12];
  const float* Wproj = (const float*)d_in[13];
  const float* bproj = (const float*)d_in[14];
  const float* lnf_g = (const float*)d_in[15];
  const float* lnf_b = (const float*)d_in[16];

  char* p = (char*)d_ws;
  __hip_bfloat16* WqkvT = (__hip_bfloat16*)p; p += (size_t)NL_ * 3 * H_ * H_ * 2;
  __hip_bfloat16* WoT = (__hip_bfloat16*)p;   p += (size_t)NL_ * H_ * H_ * 2;
  __hip_bfloat16* WfcT = (__hip_bfloat16*)p;  p += (size_t)NL_ * F_ * H_ * 2;
  __hip_bfloat16* WprojT = (__hip_bfloat16*)p; p += (size_t)NL_ * H_ * F_ * 2;
  __hip_bfloat16* embb = (__hip_bfloat16*)p;  p += (size_t)V_ * H_ * 2;
  float* x = (float*)p;                        p += (size_t)B_ * S_ * H_ * 4;
  __hip_bfloat16* h = (__hip_bfloat16*)p;     p += (size_t)B_ * S_ * H_ * 2;
  __hip_bfloat16* qkv = (__hip_bfloat16*)p;   p += (size_t)B_ * S_ * 3 * H_ * 2;
  __hip_bfloat16* g = (__hip_bfloat16*)p;     p += (size_t)B_ * S_ * F_ * 2;

  dim3 tb(32, 8);
  transpose_cvt<<<dim3(3 * H_ / 32, H_ / 32, NL_), tb, 0, stream>>>(Wqkv, WqkvT, H_, 3 * H_);
  transpose_cvt<<<dim3(H_ / 32, H_ / 32, NL_), tb, 0, stream>>>(Wo, WoT, H_, H_);
  transpose_cvt<<<dim3(F_ / 32, H_ / 32, NL_), tb, 0, stream>>>(Wfc, WfcT, H_, F_);
  transpose_cvt<<<dim3(H_ / 32, F_ / 32, NL_), tb, 0, stream>>>(Wproj, WprojT, F_, H_);
  cvt_bf16<<<V_ * H_ / 1024, 256, 0, stream>>>(emb, embb);
  embed_k<<<B_ * S_, 256, 0, stream>>>(ids, emb, x);

  const int M = B_ * S_;
  for (int l = 0; l < NL_; l++) {
    ln_k<<<M, 256, 0, stream>>>(x, ln1_g + l * H_, ln1_b + l * H_, h);
    gemm_bt<0, 4><<<(M / 128) * (3 * H_ / 128), 256, 0, stream>>>(
        h, WqkvT + (size_t)l * 3 * H_ * H_, bqkv + l * 3 * H_, qkv, M, 3 * H_, H_);
    attn_mfma<<<B_ * NH_ * (S_ / 64), 256, 0, stream>>>(qkv, sp, h);
    gemm_bt<3, 2><<<(M / 64) * (H_ / 128), 256, 0, stream>>>(
        h, WoT + (size_t)l * H_ * H_, bo + l * H_, x, M, H_, H_);
    ln_k<<<M, 256, 0, stream>>>(x, ln2_g + l * H_, ln2_b + l * H_, h);
    gemm_bt<1, 4><<<(M / 128) * (F_ / 128), 256, 0, stream>>>(
        h, WfcT + (size_t)l * F_ * H_, bfc + l * F_, g, M, F_, H_);
    gemm_bt<3, 2><<<(M / 64) * (H_ / 128), 256, 0, stream>>>(
        g, WprojT + (size_t)l * H_ * F_, bproj + l * H_, x, M, H_, F_);
  }
  ln_k<<<M, 256, 0, stream>>>(x, lnf_g, lnf_b, h);
  gemm_bt<2, 4><<<(M / 128) * (V_ / 128), 256, 0, stream>>>(h, embb, nullptr, d_out, M, V_, H_);
}